// Round 19
// baseline (225.308 us; speedup 1.0000x reference)
//
#include <hip/hip_runtime.h>
#include <hip/hip_bf16.h>
#include <stdint.h>

// B=16, TH=TS=HS=WS=1024
// res[b,i,o] = sum_j softmax_j(hp[b,i,:].sp[b,j,:]) * hp[b,j,o]
// hp = h*Wh^T + bh ; sp = s*Ws^T + bs
// R19: G1/G2 run as SWZ batched GEMMs (hp_b = h_b*Wh^T), grid (4,4,16) —
// structurally identical to G3/G4 which measure 28-30us vs PIN's 49-52us.
// cvt_pin's XCD row-ownership == SWZ's batch->XCD map (producer aligned).
// hpT epilogue batch index fixed for SWZ (batch + (gt>>10)).

typedef _Float16 half_t;
typedef __attribute__((ext_vector_type(8))) _Float16 half8;   // 4 VGPR
typedef __attribute__((ext_vector_type(4))) _Float16 half4;
typedef __attribute__((ext_vector_type(4))) float floatx4;

__device__ __forceinline__ void gl2lds16(const void* g, void* l) {
    __builtin_amdgcn_global_load_lds(
        (const __attribute__((address_space(1))) uint32_t*)(uintptr_t)g,
        (__attribute__((address_space(3))) uint32_t*)(uintptr_t)l,
        16, 0, 0);
}

#define NT16 16   // K = 1024, BK = 64

// C[r][c] = sum_k A[r][k]*B[c][k] (+bias[c]); operands K-major (B^T GEMM).
// 256x256 tile, 8 waves (2Mx4N), per-wave 128x64, double-buffered 128KB LDS.
// Swizzle: rows are 128B (=32 banks); XOR byte bits 4-6 with row&7.
// SWZ: grid (4,4,16); batch remapped so a batch's 16 tiles share one XCD.
template<int WF32, int WH16, int WH16T, int SWZ>
__global__ __launch_bounds__(512, 2) void gemm256(
    const half_t* __restrict__ A, const half_t* __restrict__ B,
    const float* __restrict__ bias,
    float* __restrict__ Cf, half_t* __restrict__ Ch, half_t* __restrict__ ChT,
    int lda, int ldb, int N,
    long aBatch, long bBatch, long cfBatch, int ldcf)
{
    extern __shared__ char smem[];   // [2][ A:32KB | B:32KB ] = 128KB

    const int tid  = threadIdx.x;
    const int wave = tid >> 6;
    const int lane = tid & 63;
    const int wr = wave >> 2;        // 0..1 -> rows wr*128..+127
    const int wc = wave & 3;         // 0..3 -> cols wc*64..+63
    const int lr = lane & 15, lg = lane >> 4;

    long batch; int row0, col0;
    if constexpr (SWZ) {
        const int lin = blockIdx.x + (blockIdx.y << 2) + (blockIdx.z << 4);
        const int xcd = lin & 7, per = lin >> 3;          // 32 blocks per XCD
        batch = (xcd << 1) | (per >> 4);                  // 2 batches per XCD
        const int wt = per & 15;
        row0 = (wt & 3) * 256;
        col0 = (wt >> 2) * 256;
    } else {
        batch = blockIdx.z;
        row0 = blockIdx.x * 256;
        col0 = blockIdx.y * 256;
    }

    const half_t* Ab = A + batch * aBatch;
    const half_t* Bb = B + batch * bBatch;

    floatx4 acc[8][4];
#pragma unroll
    for (int m = 0; m < 8; ++m)
#pragma unroll
        for (int n = 0; n < 4; ++n)
            acc[m][n] = (floatx4){0.f, 0.f, 0.f, 0.f};

    // hoisted stage source offsets (pre-swizzled global src for gl2lds):
    long aOff[2][2], bOff[2][2];
#pragma unroll
    for (int hh = 0; hh < 2; ++hh)
#pragma unroll
        for (int i = 0; i < 2; ++i) {
            const int off = hh * 16384 + i * 8192 + tid * 16;
            const int e = off ^ (((off >> 7) & 7) << 4);
            const int r = e >> 7, cb = e & 127;
            aOff[hh][i] = (long)(row0 + r) * (long)(lda * 2) + cb;
            bOff[hh][i] = (long)(col0 + r) * (long)(ldb * 2) + cb;
        }

    const int wave_s = __builtin_amdgcn_readfirstlane(wave);
    auto stage = [&](int buf, int kk) {
#pragma unroll
        for (int hh = 0; hh < 2; ++hh)
#pragma unroll
            for (int i = 0; i < 2; ++i)
                gl2lds16((const char*)Ab + aOff[hh][i] + (long)kk * 2,
                         smem + buf * 65536 + hh * 16384 + i * 8192 + wave_s * 1024);
#pragma unroll
        for (int hh = 0; hh < 2; ++hh)
#pragma unroll
            for (int i = 0; i < 2; ++i)
                gl2lds16((const char*)Bb + bOff[hh][i] + (long)kk * 2,
                         smem + buf * 65536 + 32768 + hh * 16384 + i * 8192 + wave_s * 1024);
    };

    // fragment-read bases (swizzle folded)
    uint32_t aof0 = (uint32_t)((wr * 128 + lr) * 128 + ((lg * 16) ^ ((lr & 7) << 4)));
    uint32_t aof1 = (uint32_t)((wr * 128 + lr) * 128 + ((64 + lg * 16) ^ ((lr & 7) << 4)));
    uint32_t bof0 = (uint32_t)(32768 + (wc * 64 + lr) * 128 + ((lg * 16) ^ ((lr & 7) << 4)));
    uint32_t bof1 = (uint32_t)(32768 + (wc * 64 + lr) * 128 + ((64 + lg * 16) ^ ((lr & 7) << 4)));

    stage(0, 0);
    __syncthreads();

    for (int t = 0; t < NT16; ++t) {
        if (t + 1 < NT16) stage((t & 1) ^ 1, (t + 1) * 64);   // T3: stage first

        half8 aF[4][2], bF[4][2];
#pragma unroll
        for (int ni = 0; ni < 4; ++ni) {
            bF[ni][0] = *(const half8*)(smem + bof0 + ni * 2048);
            bF[ni][1] = *(const half8*)(smem + bof1 + ni * 2048);
        }
#pragma unroll
        for (int mi = 0; mi < 4; ++mi) {
            aF[mi][0] = *(const half8*)(smem + aof0 + mi * 2048);
            aF[mi][1] = *(const half8*)(smem + aof1 + mi * 2048);
        }
#pragma unroll
        for (int mi = 0; mi < 4; ++mi)
#pragma unroll
            for (int ni = 0; ni < 4; ++ni)
#pragma unroll
                for (int ks = 0; ks < 2; ++ks)
                    acc[mi][ni] = __builtin_amdgcn_mfma_f32_16x16x32_f16(
                        aF[mi][ks], bF[ni][ks], acc[mi][ni], 0, 0, 0);
#pragma unroll
        for (int mi = 0; mi < 4; ++mi) {
            aF[mi][0] = *(const half8*)(smem + aof0 + (4 + mi) * 2048);
            aF[mi][1] = *(const half8*)(smem + aof1 + (4 + mi) * 2048);
        }
#pragma unroll
        for (int mi = 0; mi < 4; ++mi)
#pragma unroll
            for (int ni = 0; ni < 4; ++ni)
#pragma unroll
                for (int ks = 0; ks < 2; ++ks)
                    acc[4 + mi][ni] = __builtin_amdgcn_mfma_f32_16x16x32_f16(
                        aF[mi][ks], bF[ni][ks], acc[4 + mi][ni], 0, 0, 0);

        __syncthreads();
        aof0 ^= 65536; aof1 ^= 65536; bof0 ^= 65536; bof1 ^= 65536;
    }

    // ---- epilogue: transpose acc through LDS for coalesced 16B stores.
    {
        float* wlds = (float*)(smem + wave * 2304);   // per-wave 16x36 f32
        float bv[4];
#pragma unroll
        for (int n = 0; n < 4; ++n)
            bv[n] = bias ? bias[col0 + wc * 64 + n * 16 + lr] : 0.f;
        const int er = lane >> 2, ec = lane & 3;
        const int oc = lane >> 1, tc = lane & 1;
#pragma unroll
        for (int m = 0; m < 8; ++m) {
#pragma unroll
            for (int np = 0; np < 2; ++np) {
#pragma unroll
                for (int n2 = 0; n2 < 2; ++n2)
#pragma unroll
                    for (int j = 0; j < 4; ++j)
                        wlds[(lg * 4 + j) * 36 + n2 * 16 + lr] =
                            acc[m][np * 2 + n2][j] + bv[np * 2 + n2];
                const int grow = row0 + wr * 128 + m * 16;
                const int gcol = col0 + wc * 64 + np * 32;
                float4 q0 = *(float4*)&wlds[er * 36 + ec * 8];
                float4 q1 = *(float4*)&wlds[er * 36 + ec * 8 + 4];
                if (WF32) {
                    float* p = Cf + batch * cfBatch + (long)(grow + er) * ldcf + gcol + ec * 8;
                    *(float4*)p = q0;
                    *(float4*)(p + 4) = q1;
                }
                if (WH16) {
                    half8 o = { (half_t)q0.x, (half_t)q0.y, (half_t)q0.z, (half_t)q0.w,
                                (half_t)q1.x, (half_t)q1.y, (half_t)q1.z, (half_t)q1.w };
                    *(half8*)&Ch[batch * cfBatch + (long)(grow + er) * N + gcol + ec * 8] = o;
                }
                if (WH16T) {
                    float tv[8];
#pragma unroll
                    for (int k = 0; k < 8; ++k)
                        tv[k] = wlds[(tc * 8 + k) * 36 + oc];
                    half8 o = { (half_t)tv[0], (half_t)tv[1], (half_t)tv[2], (half_t)tv[3],
                                (half_t)tv[4], (half_t)tv[5], (half_t)tv[6], (half_t)tv[7] };
                    const int gt = grow + tc * 8;
                    *(half8*)&ChT[(batch + (long)(gt >> 10)) * 1048576
                                  + (long)(gcol + oc) * 1024 + (gt & 1023)] = o;
                }
                __builtin_amdgcn_s_waitcnt(0);   // drain before next overwrite of wlds
            }
        }
    }
}

// In-place fp16 softmax, plain row order.
__global__ void softmax_h(half_t* __restrict__ S) {
    const long r = blockIdx.x;
    half_t* row = S + r * 1024;
    const int tid = threadIdx.x;
    const int wave = tid >> 6, lane = tid & 63;

    half4 h4 = ((const half4*)row)[tid];
    float v0 = (float)h4[0], v1 = (float)h4[1], v2 = (float)h4[2], v3 = (float)h4[3];
    float mx = fmaxf(fmaxf(v0, v1), fmaxf(v2, v3));
#pragma unroll
    for (int off = 32; off > 0; off >>= 1)
        mx = fmaxf(mx, __shfl_xor(mx, off));
    __shared__ float rmx[4], rsm[4];
    if (lane == 0) rmx[wave] = mx;
    __syncthreads();
    mx = fmaxf(fmaxf(rmx[0], rmx[1]), fmaxf(rmx[2], rmx[3]));

    float e0 = __expf(v0 - mx), e1 = __expf(v1 - mx);
    float e2 = __expf(v2 - mx), e3 = __expf(v3 - mx);
    float s = e0 + e1 + e2 + e3;
#pragma unroll
    for (int off = 32; off > 0; off >>= 1)
        s += __shfl_xor(s, off);
    if (lane == 0) rsm[wave] = s;
    __syncthreads();
    s = rsm[0] + rsm[1] + rsm[2] + rsm[3];

    const float inv = 1.0f / s;
    half4 o = { (half_t)(e0 * inv), (half_t)(e1 * inv), (half_t)(e2 * inv), (half_t)(e3 * inv) };
    ((half4*)row)[tid] = o;
}

// f32 -> fp16 cvt, XCD-pinned rows: block l handles 8 rows starting at
// 2048*(l&7) + 8*(l>>3)  (XCD r cvts rows [2048r, 2048r+2048) = batches 2r,2r+1).
__global__ void cvt_pin(const float4* __restrict__ src, half4* __restrict__ dst) {
    const int l = blockIdx.x;                       // 2048 blocks
    const long base = (2048L * (l & 7) + 8L * (l >> 3)) * 256;  // float4 units
    const int tid = threadIdx.x;                    // 256 threads
#pragma unroll
    for (int k = 0; k < 8; ++k) {
        float4 v = src[base + k * 256 + tid];
        half4 o = { (half_t)v.x, (half_t)v.y, (half_t)v.z, (half_t)v.w };
        dst[base + k * 256 + tid] = o;
    }
}

// both weight matrices in one dispatch (1024 blocks x 256 thr, 1 float4 each x2)
__global__ void cvt_w2(const float4* __restrict__ w1, half4* __restrict__ d1,
                       const float4* __restrict__ w2, half4* __restrict__ d2) {
    const int i = blockIdx.x * 256 + threadIdx.x;   // 262144 float4s per matrix
    const float4 a = w1[i];
    d1[i] = (half4){ (half_t)a.x, (half_t)a.y, (half_t)a.z, (half_t)a.w };
    const float4 b = w2[i];
    d2[i] = (half4){ (half_t)b.x, (half_t)b.y, (half_t)b.z, (half_t)b.w };
}

extern "C" void kernel_launch(void* const* d_in, const int* in_sizes, int n_in,
                              void* d_out, int out_size, void* d_ws, size_t ws_size,
                              hipStream_t stream) {
    const float* h  = (const float*)d_in[0];
    const float* s  = (const float*)d_in[1];
    const float* Wh = (const float*)d_in[2];
    const float* bh = (const float*)d_in[3];
    const float* Ws = (const float*)d_in[4];
    const float* bs = (const float*)d_in[5];

    const long MB = 16384;   // B*TH
    const long D  = 1024;

    // workspace carve (~196 MB)
    char* w = (char*)d_ws;
    half_t* sc16 = (half_t*)w;  w += MB * D * 2;   // 32MB fp16 scores/probs
    half_t* Wh16 = (half_t*)w;  w += D * D * 2;
    half_t* Ws16 = (half_t*)w;  w += D * D * 2;
    half_t* h16  = (half_t*)w;  w += MB * D * 2;
    half_t* s16  = (half_t*)w;  w += MB * D * 2;
    half_t* hp16 = (half_t*)w;  w += MB * D * 2;
    half_t* sp16 = (half_t*)w;  w += MB * D * 2;
    half_t* hpT  = (half_t*)w;  w += MB * D * 2;   // [16][o][t]

    (void)hipFuncSetAttribute(reinterpret_cast<const void*>(&gemm256<0,1,1,1>),
                        hipFuncAttributeMaxDynamicSharedMemorySize, 131072);
    (void)hipFuncSetAttribute(reinterpret_cast<const void*>(&gemm256<0,1,0,1>),
                        hipFuncAttributeMaxDynamicSharedMemorySize, 131072);
    (void)hipFuncSetAttribute(reinterpret_cast<const void*>(&gemm256<1,0,0,1>),
                        hipFuncAttributeMaxDynamicSharedMemorySize, 131072);

    cvt_w2<<<1024, 256, 0, stream>>>((const float4*)Wh, (half4*)Wh16,
                                     (const float4*)Ws, (half4*)Ws16);

    // cvt h (XCD-pinned) then G1: hp_b = h_b*Wh^T + bh, SWZ batched (+hpT)
    cvt_pin<<<2048, 256, 0, stream>>>((const float4*)h, (half4*)h16);
    gemm256<0,1,1,1><<<dim3(4, 4, 16), 512, 131072, stream>>>(
        h16, Wh16, bh, nullptr, hp16, hpT, 1024, 1024, 1024,
        1048576L, 0L, 1048576L, 0);

    // cvt s then G2: sp_b = s_b*Ws^T + bs, SWZ batched
    cvt_pin<<<2048, 256, 0, stream>>>((const float4*)s, (half4*)s16);
    gemm256<0,1,0,1><<<dim3(4, 4, 16), 512, 131072, stream>>>(
        s16, Ws16, bs, nullptr, sp16, nullptr, 1024, 1024, 1024,
        1048576L, 0L, 1048576L, 0);

    // GEMM3: scores[b] = hp_b * sp_b^T -> fp16, XCD-batch swizzle
    gemm256<0,1,0,1><<<dim3(4, 4, 16), 512, 131072, stream>>>(
        hp16, sp16, nullptr, nullptr, sc16, nullptr, 1024, 1024, 1024,
        1048576L, 1048576L, 1048576L, 0);
    // softmax over j, fp16 in place
    softmax_h<<<16384, 256, 0, stream>>>(sc16);
    // GEMM4: out[b] = probs_b * hpT_b^T (f32 -> d_out), XCD-batch swizzle
    gemm256<1,0,0,1><<<dim3(4, 4, 16), 512, 131072, stream>>>(
        sc16, hpT, nullptr, (float*)d_out, nullptr, nullptr,
        1024, 1024, 1024, 1048576L, 1048576L, 1048576L, 1024);
}

// Round 20
// 223.923 us; speedup vs baseline: 1.0062x; 1.0062x over previous
//
#include <hip/hip_runtime.h>
#include <hip/hip_bf16.h>
#include <stdint.h>

// B=16, TH=TS=HS=WS=1024
// res[b,i,o] = sum_j softmax_j(hp[b,i,:].sp[b,j,:]) * hp[b,j,o]
// hp = h*Wh^T + bh ; sp = s*Ws^T + bs
// R20 = R19 + coalesced hpT epilogue: per-wave 16KB LDS transpose buffer
// ([o][t] fp16, XOR bits4-6 by o&7), global stores 256B-contiguous per o-row
// (4 rows/instr) instead of 64 scattered 16B stores (1.8x write amp).

typedef _Float16 half_t;
typedef __attribute__((ext_vector_type(8))) _Float16 half8;   // 4 VGPR
typedef __attribute__((ext_vector_type(4))) _Float16 half4;
typedef __attribute__((ext_vector_type(4))) float floatx4;

__device__ __forceinline__ void gl2lds16(const void* g, void* l) {
    __builtin_amdgcn_global_load_lds(
        (const __attribute__((address_space(1))) uint32_t*)(uintptr_t)g,
        (__attribute__((address_space(3))) uint32_t*)(uintptr_t)l,
        16, 0, 0);
}

#define NT16 16   // K = 1024, BK = 64

// C[r][c] = sum_k A[r][k]*B[c][k] (+bias[c]); operands K-major (B^T GEMM).
// 256x256 tile, 8 waves (2Mx4N), per-wave 128x64, double-buffered 128KB LDS.
// Swizzle: rows are 128B (=32 banks); XOR byte bits 4-6 with row&7.
// SWZ: grid (4,4,16); batch remapped so a batch's 16 tiles share one XCD.
template<int WF32, int WH16, int WH16T, int SWZ>
__global__ __launch_bounds__(512, 2) void gemm256(
    const half_t* __restrict__ A, const half_t* __restrict__ B,
    const float* __restrict__ bias,
    float* __restrict__ Cf, half_t* __restrict__ Ch, half_t* __restrict__ ChT,
    int lda, int ldb, int N,
    long aBatch, long bBatch, long cfBatch, int ldcf)
{
    extern __shared__ char smem[];   // [2][ A:32KB | B:32KB ] = 128KB

    const int tid  = threadIdx.x;
    const int wave = tid >> 6;
    const int lane = tid & 63;
    const int wr = wave >> 2;        // 0..1 -> rows wr*128..+127
    const int wc = wave & 3;         // 0..3 -> cols wc*64..+63
    const int lr = lane & 15, lg = lane >> 4;

    long batch; int row0, col0;
    if constexpr (SWZ) {
        const int lin = blockIdx.x + (blockIdx.y << 2) + (blockIdx.z << 4);
        const int xcd = lin & 7, per = lin >> 3;          // 32 blocks per XCD
        batch = (xcd << 1) | (per >> 4);                  // 2 batches per XCD
        const int wt = per & 15;
        row0 = (wt & 3) * 256;
        col0 = (wt >> 2) * 256;
    } else {
        batch = blockIdx.z;
        row0 = blockIdx.x * 256;
        col0 = blockIdx.y * 256;
    }

    const half_t* Ab = A + batch * aBatch;
    const half_t* Bb = B + batch * bBatch;

    floatx4 acc[8][4];
#pragma unroll
    for (int m = 0; m < 8; ++m)
#pragma unroll
        for (int n = 0; n < 4; ++n)
            acc[m][n] = (floatx4){0.f, 0.f, 0.f, 0.f};

    // hoisted stage source offsets (pre-swizzled global src for gl2lds):
    long aOff[2][2], bOff[2][2];
#pragma unroll
    for (int hh = 0; hh < 2; ++hh)
#pragma unroll
        for (int i = 0; i < 2; ++i) {
            const int off = hh * 16384 + i * 8192 + tid * 16;
            const int e = off ^ (((off >> 7) & 7) << 4);
            const int r = e >> 7, cb = e & 127;
            aOff[hh][i] = (long)(row0 + r) * (long)(lda * 2) + cb;
            bOff[hh][i] = (long)(col0 + r) * (long)(ldb * 2) + cb;
        }

    const int wave_s = __builtin_amdgcn_readfirstlane(wave);
    auto stage = [&](int buf, int kk) {
#pragma unroll
        for (int hh = 0; hh < 2; ++hh)
#pragma unroll
            for (int i = 0; i < 2; ++i)
                gl2lds16((const char*)Ab + aOff[hh][i] + (long)kk * 2,
                         smem + buf * 65536 + hh * 16384 + i * 8192 + wave_s * 1024);
#pragma unroll
        for (int hh = 0; hh < 2; ++hh)
#pragma unroll
            for (int i = 0; i < 2; ++i)
                gl2lds16((const char*)Bb + bOff[hh][i] + (long)kk * 2,
                         smem + buf * 65536 + 32768 + hh * 16384 + i * 8192 + wave_s * 1024);
    };

    // fragment-read bases (swizzle folded)
    uint32_t aof0 = (uint32_t)((wr * 128 + lr) * 128 + ((lg * 16) ^ ((lr & 7) << 4)));
    uint32_t aof1 = (uint32_t)((wr * 128 + lr) * 128 + ((64 + lg * 16) ^ ((lr & 7) << 4)));
    uint32_t bof0 = (uint32_t)(32768 + (wc * 64 + lr) * 128 + ((lg * 16) ^ ((lr & 7) << 4)));
    uint32_t bof1 = (uint32_t)(32768 + (wc * 64 + lr) * 128 + ((64 + lg * 16) ^ ((lr & 7) << 4)));

    stage(0, 0);
    __syncthreads();

    for (int t = 0; t < NT16; ++t) {
        if (t + 1 < NT16) stage((t & 1) ^ 1, (t + 1) * 64);   // T3: stage first

        half8 aF[4][2], bF[4][2];
#pragma unroll
        for (int ni = 0; ni < 4; ++ni) {
            bF[ni][0] = *(const half8*)(smem + bof0 + ni * 2048);
            bF[ni][1] = *(const half8*)(smem + bof1 + ni * 2048);
        }
#pragma unroll
        for (int mi = 0; mi < 4; ++mi) {
            aF[mi][0] = *(const half8*)(smem + aof0 + mi * 2048);
            aF[mi][1] = *(const half8*)(smem + aof1 + mi * 2048);
        }
#pragma unroll
        for (int mi = 0; mi < 4; ++mi)
#pragma unroll
            for (int ni = 0; ni < 4; ++ni)
#pragma unroll
                for (int ks = 0; ks < 2; ++ks)
                    acc[mi][ni] = __builtin_amdgcn_mfma_f32_16x16x32_f16(
                        aF[mi][ks], bF[ni][ks], acc[mi][ni], 0, 0, 0);
#pragma unroll
        for (int mi = 0; mi < 4; ++mi) {
            aF[mi][0] = *(const half8*)(smem + aof0 + (4 + mi) * 2048);
            aF[mi][1] = *(const half8*)(smem + aof1 + (4 + mi) * 2048);
        }
#pragma unroll
        for (int mi = 0; mi < 4; ++mi)
#pragma unroll
            for (int ni = 0; ni < 4; ++ni)
#pragma unroll
                for (int ks = 0; ks < 2; ++ks)
                    acc[4 + mi][ni] = __builtin_amdgcn_mfma_f32_16x16x32_f16(
                        aF[mi][ks], bF[ni][ks], acc[4 + mi][ni], 0, 0, 0);

        __syncthreads();
        aof0 ^= 65536; aof1 ^= 65536; bof0 ^= 65536; bof1 ^= 65536;
    }

    // bias values for this wave's 4 n-tiles
    float bv[4];
#pragma unroll
    for (int n = 0; n < 4; ++n)
        bv[n] = bias ? bias[col0 + wc * 64 + n * 16 + lr] : 0.f;

    // ---- hpT phase (WH16T): per-wave 16KB LDS [64 o][128 t] fp16,
    // byte bits 4-6 XOR'd with o&7; then 256B-contiguous row stores
    // (lanes 0-15 = one o-row, 4 rows per instruction).
    if (WH16T) {
        char* tb = smem + wave * 16384;
#pragma unroll
        for (int m = 0; m < 8; ++m)
#pragma unroll
            for (int n = 0; n < 4; ++n) {
                const int o_l = n * 16 + lr;                  // 0..63
                const uint32_t x = (uint32_t)(o_l & 7) << 4;
                floatx4 v = acc[m][n];
                half4 pk = { (half_t)(v[0] + bv[n]), (half_t)(v[1] + bv[n]),
                             (half_t)(v[2] + bv[n]), (half_t)(v[3] + bv[n]) };
                *(half4*)(tb + o_l * 256 + (((uint32_t)(m * 32 + lg * 8)) ^ x)) = pk;
            }
        // read back + coalesced store (compiler inserts lgkm waits on reads)
#pragma unroll
        for (int seg = 0; seg < 16; ++seg) {
            const int o_l = seg * 4 + (lane >> 4);
            const uint32_t cb = (uint32_t)((lane & 15) * 16) ^ ((uint32_t)(o_l & 7) << 4);
            half8 v = *(const half8*)(tb + o_l * 256 + cb);
            const long o_g = col0 + wc * 64 + o_l;
            const int  t_g = row0 + wr * 128 + (lane & 15) * 8;
            *(half8*)&ChT[batch * 1048576 + o_g * 1024 + t_g] = v;
        }
        __builtin_amdgcn_s_waitcnt(0);   // drain before wlds reuses this region
    }

    // ---- main epilogue: transpose acc through LDS for coalesced 16B stores.
    {
        float* wlds = (float*)(smem + wave * 16384);   // own region (16x36 f32)
        const int er = lane >> 2, ec = lane & 3;
#pragma unroll
        for (int m = 0; m < 8; ++m) {
#pragma unroll
            for (int np = 0; np < 2; ++np) {
#pragma unroll
                for (int n2 = 0; n2 < 2; ++n2)
#pragma unroll
                    for (int j = 0; j < 4; ++j)
                        wlds[(lg * 4 + j) * 36 + n2 * 16 + lr] =
                            acc[m][np * 2 + n2][j] + bv[np * 2 + n2];
                const int grow = row0 + wr * 128 + m * 16;
                const int gcol = col0 + wc * 64 + np * 32;
                float4 q0 = *(float4*)&wlds[er * 36 + ec * 8];
                float4 q1 = *(float4*)&wlds[er * 36 + ec * 8 + 4];
                if (WF32) {
                    float* p = Cf + batch * cfBatch + (long)(grow + er) * ldcf + gcol + ec * 8;
                    *(float4*)p = q0;
                    *(float4*)(p + 4) = q1;
                }
                if (WH16) {
                    half8 o = { (half_t)q0.x, (half_t)q0.y, (half_t)q0.z, (half_t)q0.w,
                                (half_t)q1.x, (half_t)q1.y, (half_t)q1.z, (half_t)q1.w };
                    *(half8*)&Ch[batch * cfBatch + (long)(grow + er) * N + gcol + ec * 8] = o;
                }
                __builtin_amdgcn_s_waitcnt(0);   // drain before next overwrite of wlds
            }
        }
    }
}

// In-place fp16 softmax, plain row order.
__global__ void softmax_h(half_t* __restrict__ S) {
    const long r = blockIdx.x;
    half_t* row = S + r * 1024;
    const int tid = threadIdx.x;
    const int wave = tid >> 6, lane = tid & 63;

    half4 h4 = ((const half4*)row)[tid];
    float v0 = (float)h4[0], v1 = (float)h4[1], v2 = (float)h4[2], v3 = (float)h4[3];
    float mx = fmaxf(fmaxf(v0, v1), fmaxf(v2, v3));
#pragma unroll
    for (int off = 32; off > 0; off >>= 1)
        mx = fmaxf(mx, __shfl_xor(mx, off));
    __shared__ float rmx[4], rsm[4];
    if (lane == 0) rmx[wave] = mx;
    __syncthreads();
    mx = fmaxf(fmaxf(rmx[0], rmx[1]), fmaxf(rmx[2], rmx[3]));

    float e0 = __expf(v0 - mx), e1 = __expf(v1 - mx);
    float e2 = __expf(v2 - mx), e3 = __expf(v3 - mx);
    float s = e0 + e1 + e2 + e3;
#pragma unroll
    for (int off = 32; off > 0; off >>= 1)
        s += __shfl_xor(s, off);
    if (lane == 0) rsm[wave] = s;
    __syncthreads();
    s = rsm[0] + rsm[1] + rsm[2] + rsm[3];

    const float inv = 1.0f / s;
    half4 o = { (half_t)(e0 * inv), (half_t)(e1 * inv), (half_t)(e2 * inv), (half_t)(e3 * inv) };
    ((half4*)row)[tid] = o;
}

// f32 -> fp16 cvt, XCD-pinned rows: block l handles 8 rows starting at
// 2048*(l&7) + 8*(l>>3)  (XCD r cvts rows [2048r, 2048r+2048) = batches 2r,2r+1).
__global__ void cvt_pin(const float4* __restrict__ src, half4* __restrict__ dst) {
    const int l = blockIdx.x;                       // 2048 blocks
    const long base = (2048L * (l & 7) + 8L * (l >> 3)) * 256;  // float4 units
    const int tid = threadIdx.x;                    // 256 threads
#pragma unroll
    for (int k = 0; k < 8; ++k) {
        float4 v = src[base + k * 256 + tid];
        half4 o = { (half_t)v.x, (half_t)v.y, (half_t)v.z, (half_t)v.w };
        dst[base + k * 256 + tid] = o;
    }
}

// both weight matrices in one dispatch (1024 blocks x 256 thr, 1 float4 each x2)
__global__ void cvt_w2(const float4* __restrict__ w1, half4* __restrict__ d1,
                       const float4* __restrict__ w2, half4* __restrict__ d2) {
    const int i = blockIdx.x * 256 + threadIdx.x;   // 262144 float4s per matrix
    const float4 a = w1[i];
    d1[i] = (half4){ (half_t)a.x, (half_t)a.y, (half_t)a.z, (half_t)a.w };
    const float4 b = w2[i];
    d2[i] = (half4){ (half_t)b.x, (half_t)b.y, (half_t)b.z, (half_t)b.w };
}

extern "C" void kernel_launch(void* const* d_in, const int* in_sizes, int n_in,
                              void* d_out, int out_size, void* d_ws, size_t ws_size,
                              hipStream_t stream) {
    const float* h  = (const float*)d_in[0];
    const float* s  = (const float*)d_in[1];
    const float* Wh = (const float*)d_in[2];
    const float* bh = (const float*)d_in[3];
    const float* Ws = (const float*)d_in[4];
    const float* bs = (const float*)d_in[5];

    const long MB = 16384;   // B*TH
    const long D  = 1024;

    // workspace carve (~196 MB)
    char* w = (char*)d_ws;
    half_t* sc16 = (half_t*)w;  w += MB * D * 2;   // 32MB fp16 scores/probs
    half_t* Wh16 = (half_t*)w;  w += D * D * 2;
    half_t* Ws16 = (half_t*)w;  w += D * D * 2;
    half_t* h16  = (half_t*)w;  w += MB * D * 2;
    half_t* s16  = (half_t*)w;  w += MB * D * 2;
    half_t* hp16 = (half_t*)w;  w += MB * D * 2;
    half_t* sp16 = (half_t*)w;  w += MB * D * 2;
    half_t* hpT  = (half_t*)w;  w += MB * D * 2;   // [16][o][t]

    (void)hipFuncSetAttribute(reinterpret_cast<const void*>(&gemm256<0,1,1,1>),
                        hipFuncAttributeMaxDynamicSharedMemorySize, 131072);
    (void)hipFuncSetAttribute(reinterpret_cast<const void*>(&gemm256<0,1,0,1>),
                        hipFuncAttributeMaxDynamicSharedMemorySize, 131072);
    (void)hipFuncSetAttribute(reinterpret_cast<const void*>(&gemm256<1,0,0,1>),
                        hipFuncAttributeMaxDynamicSharedMemorySize, 131072);

    cvt_w2<<<1024, 256, 0, stream>>>((const float4*)Wh, (half4*)Wh16,
                                     (const float4*)Ws, (half4*)Ws16);

    // cvt h (XCD-pinned) then G1: hp_b = h_b*Wh^T + bh, SWZ batched (+hpT)
    cvt_pin<<<2048, 256, 0, stream>>>((const float4*)h, (half4*)h16);
    gemm256<0,1,1,1><<<dim3(4, 4, 16), 512, 131072, stream>>>(
        h16, Wh16, bh, nullptr, hp16, hpT, 1024, 1024, 1024,
        1048576L, 0L, 1048576L, 0);

    // cvt s then G2: sp_b = s_b*Ws^T + bs, SWZ batched
    cvt_pin<<<2048, 256, 0, stream>>>((const float4*)s, (half4*)s16);
    gemm256<0,1,0,1><<<dim3(4, 4, 16), 512, 131072, stream>>>(
        s16, Ws16, bs, nullptr, sp16, nullptr, 1024, 1024, 1024,
        1048576L, 0L, 1048576L, 0);

    // GEMM3: scores[b] = hp_b * sp_b^T -> fp16, XCD-batch swizzle
    gemm256<0,1,0,1><<<dim3(4, 4, 16), 512, 131072, stream>>>(
        hp16, sp16, nullptr, nullptr, sc16, nullptr, 1024, 1024, 1024,
        1048576L, 1048576L, 1048576L, 0);
    // softmax over j, fp16 in place
    softmax_h<<<16384, 256, 0, stream>>>(sc16);
    // GEMM4: out[b] = probs_b * hpT_b^T (f32 -> d_out), XCD-batch swizzle
    gemm256<1,0,0,1><<<dim3(4, 4, 16), 512, 131072, stream>>>(
        sc16, hpT, nullptr, (float*)d_out, nullptr, nullptr,
        1024, 1024, 1024, 1048576L, 1048576L, 1048576L, 1024);
}

// Round 21
// 209.230 us; speedup vs baseline: 1.0768x; 1.0702x over previous
//
#include <hip/hip_runtime.h>
#include <hip/hip_bf16.h>
#include <stdint.h>

// B=16, TH=TS=HS=WS=1024
// res[b,i,o] = sum_j softmax_j(hp[b,i,:].sp[b,j,:]) * hp[b,j,o]
// hp = h*Wh^T + bh ; sp = s*Ws^T + bs
// R21 = R16 (best: 216us; RSA G1/G2, fp16 scores, SWZ G3/G4)
//  + coalesced hpT epilogue (R20-proven: per-wave 16KB LDS [o][t], 256B row
//    stores, -6us on G1)  + merged weight cvt (one dispatch).

typedef _Float16 half_t;
typedef __attribute__((ext_vector_type(8))) _Float16 half8;   // 4 VGPR
typedef __attribute__((ext_vector_type(4))) _Float16 half4;
typedef __attribute__((ext_vector_type(4))) float floatx4;

__device__ __forceinline__ void gl2lds16(const void* g, void* l) {
    __builtin_amdgcn_global_load_lds(
        (const __attribute__((address_space(1))) uint32_t*)(uintptr_t)g,
        (__attribute__((address_space(3))) uint32_t*)(uintptr_t)l,
        16, 0, 0);
}

#define NT16 16   // K = 1024, BK = 64

// C[r][c] = sum_k A[r][k]*B[c][k] (+bias[c]); operands K-major (B^T GEMM).
// 256x256 tile, 8 waves (2Mx4N), per-wave 128x64, double-buffered 128KB LDS.
// Swizzle: rows are 128B (=32 banks); XOR byte bits 4-6 with row&7.
// RSA: A staged from f32 global (load->cvt->swizzled ds_write).
// SWZ: grid (4,4,16); batch remapped so a batch's 16 tiles share one XCD.
template<int WF32, int WH16, int WH16T, int RSA, int SWZ>
__global__ __launch_bounds__(512, 2) void gemm256(
    const half_t* __restrict__ A, const float* __restrict__ A32,
    const half_t* __restrict__ B,
    const float* __restrict__ bias,
    float* __restrict__ Cf, half_t* __restrict__ Ch, half_t* __restrict__ ChT,
    int lda, int ldb, int N,
    long aBatch, long bBatch, long cfBatch, int ldcf)
{
    extern __shared__ char smem[];   // [2][ A:32KB | B:32KB ] = 128KB

    const int tid  = threadIdx.x;
    const int wave = tid >> 6;
    const int lane = tid & 63;
    const int wr = wave >> 2;        // 0..1 -> rows wr*128..+127
    const int wc = wave & 3;         // 0..3 -> cols wc*64..+63
    const int lr = lane & 15, lg = lane >> 4;

    long batch; int row0, col0;
    if constexpr (SWZ) {
        const int lin = blockIdx.x + (blockIdx.y << 2) + (blockIdx.z << 4);
        const int xcd = lin & 7, per = lin >> 3;          // 32 blocks per XCD
        batch = (xcd << 1) | (per >> 4);                  // 2 batches per XCD
        const int wt = per & 15;
        row0 = (wt & 3) * 256;
        col0 = (wt >> 2) * 256;
    } else {
        batch = blockIdx.z;
        row0 = blockIdx.x * 256;
        col0 = blockIdx.y * 256;
    }

    const half_t* Bb = B + batch * bBatch;

    floatx4 acc[8][4];
#pragma unroll
    for (int m = 0; m < 8; ++m)
#pragma unroll
        for (int n = 0; n < 4; ++n)
            acc[m][n] = (floatx4){0.f, 0.f, 0.f, 0.f};

    // hoisted B stage source offsets (pre-swizzled global src for gl2lds):
    long bOff[2][2];
    long aOffG[2][2];                 // A gl2lds path (non-RSA)
#pragma unroll
    for (int hh = 0; hh < 2; ++hh)
#pragma unroll
        for (int i = 0; i < 2; ++i) {
            const int off = hh * 16384 + i * 8192 + tid * 16;
            const int e = off ^ (((off >> 7) & 7) << 4);
            const int r = e >> 7, cb = e & 127;
            bOff[hh][i] = (long)(col0 + r) * (long)(ldb * 2) + cb;
            if constexpr (!RSA)
                aOffG[hh][i] = (long)(row0 + r) * (long)(lda * 2) + cb;
        }

    const int wave_s = __builtin_amdgcn_readfirstlane(wave);
    auto stageB = [&](int buf, int kk) {
#pragma unroll
        for (int hh = 0; hh < 2; ++hh)
#pragma unroll
            for (int i = 0; i < 2; ++i)
                gl2lds16((const char*)Bb + bOff[hh][i] + (long)kk * 2,
                         smem + buf * 65536 + 32768 + hh * 16384 + i * 8192 + wave_s * 1024);
    };
    auto stageA16 = [&](int buf, int kk) {   // non-RSA: fp16 A via gl2lds
        const half_t* Ab = A + batch * aBatch;
#pragma unroll
        for (int hh = 0; hh < 2; ++hh)
#pragma unroll
            for (int i = 0; i < 2; ++i)
                gl2lds16((const char*)Ab + aOffG[hh][i] + (long)kk * 2,
                         smem + buf * 65536 + hh * 16384 + i * 8192 + wave_s * 1024);
    };

    // RSA chunk coords (4 chunks x 16B fp16 per thread)
    int rsaRow[4], rsaKb[4];
#pragma unroll
    for (int c = 0; c < 4; ++c) {
        const int off = c * 8192 + tid * 16;
        rsaRow[c] = off >> 7;
        rsaKb[c]  = off & 127;
    }

    // fragment-read bases (swizzle folded)
    uint32_t aof0 = (uint32_t)((wr * 128 + lr) * 128 + ((lg * 16) ^ ((lr & 7) << 4)));
    uint32_t aof1 = (uint32_t)((wr * 128 + lr) * 128 + ((64 + lg * 16) ^ ((lr & 7) << 4)));
    uint32_t bof0 = (uint32_t)(32768 + (wc * 64 + lr) * 128 + ((lg * 16) ^ ((lr & 7) << 4)));
    uint32_t bof1 = (uint32_t)(32768 + (wc * 64 + lr) * 128 + ((64 + lg * 16) ^ ((lr & 7) << 4)));

    // staging of A for RSA: load 8xfloat4 -> cvt -> 4x ds_write_b128 (swizzled)
    auto rsaLoad = [&](float4 (&fv)[4][2], int kk) {
#pragma unroll
        for (int c = 0; c < 4; ++c) {
            const float* src = A32 + batch * aBatch
                             + (long)(row0 + rsaRow[c]) * lda + kk + (rsaKb[c] >> 1);
            fv[c][0] = *(const float4*)src;
            fv[c][1] = *(const float4*)(src + 4);
        }
    };
    auto rsaWrite = [&](float4 (&fv)[4][2], int buf) {
#pragma unroll
        for (int c = 0; c < 4; ++c) {
            half8 o = { (half_t)fv[c][0].x, (half_t)fv[c][0].y, (half_t)fv[c][0].z, (half_t)fv[c][0].w,
                        (half_t)fv[c][1].x, (half_t)fv[c][1].y, (half_t)fv[c][1].z, (half_t)fv[c][1].w };
            *(half8*)(smem + buf * 65536 + rsaRow[c] * 128
                      + (rsaKb[c] ^ ((rsaRow[c] & 7) << 4))) = o;
        }
    };

    // ---- prologue: stage tile 0, sync.
    if constexpr (RSA) {
        float4 fv[4][2];
        rsaLoad(fv, 0);
        stageB(0, 0);
        rsaWrite(fv, 0);
    } else {
        stageA16(0, 0);
        stageB(0, 0);
    }
    __syncthreads();

    for (int t = 0; t < NT16; ++t) {
        const int nxt = (t & 1) ^ 1;
        const int k1 = (t + 1) * 64;

        // (1) issue next-tile staging loads first (T3 recipe)
        float4 fv[4][2];
        if (t + 1 < NT16) {
            if constexpr (RSA) {
                rsaLoad(fv, k1);     // f32 loads in flight; writes deferred below
                stageB(nxt, k1);
            } else {
                stageA16(nxt, k1);
                stageB(nxt, k1);
            }
        }

        // (2) ds_reads of tile t
        half8 aF[4][2], bF[4][2];
#pragma unroll
        for (int ni = 0; ni < 4; ++ni) {
            bF[ni][0] = *(const half8*)(smem + bof0 + ni * 2048);
            bF[ni][1] = *(const half8*)(smem + bof1 + ni * 2048);
        }
#pragma unroll
        for (int mi = 0; mi < 4; ++mi) {
            aF[mi][0] = *(const half8*)(smem + aof0 + mi * 2048);
            aF[mi][1] = *(const half8*)(smem + aof1 + mi * 2048);
        }

        // (2b) RSA: convert + swizzled LDS writes for tile t+1
        if (RSA && t + 1 < NT16) rsaWrite(fv, nxt);

        // (3) MFMA of tile t (two 32-MFMA halves)
#pragma unroll
        for (int mi = 0; mi < 4; ++mi)
#pragma unroll
            for (int ni = 0; ni < 4; ++ni)
#pragma unroll
                for (int ks = 0; ks < 2; ++ks)
                    acc[mi][ni] = __builtin_amdgcn_mfma_f32_16x16x32_f16(
                        aF[mi][ks], bF[ni][ks], acc[mi][ni], 0, 0, 0);
#pragma unroll
        for (int mi = 0; mi < 4; ++mi) {
            aF[mi][0] = *(const half8*)(smem + aof0 + (4 + mi) * 2048);
            aF[mi][1] = *(const half8*)(smem + aof1 + (4 + mi) * 2048);
        }
#pragma unroll
        for (int mi = 0; mi < 4; ++mi)
#pragma unroll
            for (int ni = 0; ni < 4; ++ni)
#pragma unroll
                for (int ks = 0; ks < 2; ++ks)
                    acc[4 + mi][ni] = __builtin_amdgcn_mfma_f32_16x16x32_f16(
                        aF[mi][ks], bF[ni][ks], acc[4 + mi][ni], 0, 0, 0);

        // (4) one barrier per K-step
        __syncthreads();
        aof0 ^= 65536; aof1 ^= 65536; bof0 ^= 65536; bof1 ^= 65536;
    }

    // bias values for this wave's 4 n-tiles
    float bv[4];
#pragma unroll
    for (int n = 0; n < 4; ++n)
        bv[n] = bias ? bias[col0 + wc * 64 + n * 16 + lr] : 0.f;

    // ---- hpT phase (WH16T): per-wave 16KB LDS [64 o][128 t] fp16,
    // byte bits 4-6 XOR'd with o&7; then 256B-contiguous row stores.
    if (WH16T) {
        char* tb = smem + wave * 16384;
#pragma unroll
        for (int m = 0; m < 8; ++m)
#pragma unroll
            for (int n = 0; n < 4; ++n) {
                const int o_l = n * 16 + lr;                  // 0..63
                const uint32_t x = (uint32_t)(o_l & 7) << 4;
                floatx4 v = acc[m][n];
                half4 pk = { (half_t)(v[0] + bv[n]), (half_t)(v[1] + bv[n]),
                             (half_t)(v[2] + bv[n]), (half_t)(v[3] + bv[n]) };
                *(half4*)(tb + o_l * 256 + (((uint32_t)(m * 32 + lg * 8)) ^ x)) = pk;
            }
#pragma unroll
        for (int seg = 0; seg < 16; ++seg) {
            const int o_l = seg * 4 + (lane >> 4);
            const uint32_t cb = (uint32_t)((lane & 15) * 16) ^ ((uint32_t)(o_l & 7) << 4);
            half8 v = *(const half8*)(tb + o_l * 256 + cb);
            const long o_g = col0 + wc * 64 + o_l;
            const int  t_g = row0 + wr * 128 + (lane & 15) * 8;
            *(half8*)&ChT[(batch + (long)(t_g >> 10)) * 1048576
                          + o_g * 1024 + (t_g & 1023)] = v;
        }
        __builtin_amdgcn_s_waitcnt(0);   // drain before wlds reuses this region
    }

    // ---- main epilogue: transpose acc through LDS for coalesced 16B stores.
    {
        float* wlds = (float*)(smem + wave * 16384);   // own region (16x36 f32)
        const int er = lane >> 2, ec = lane & 3;
#pragma unroll
        for (int m = 0; m < 8; ++m) {
#pragma unroll
            for (int np = 0; np < 2; ++np) {
#pragma unroll
                for (int n2 = 0; n2 < 2; ++n2)
#pragma unroll
                    for (int j = 0; j < 4; ++j)
                        wlds[(lg * 4 + j) * 36 + n2 * 16 + lr] =
                            acc[m][np * 2 + n2][j] + bv[np * 2 + n2];
                const int grow = row0 + wr * 128 + m * 16;
                const int gcol = col0 + wc * 64 + np * 32;
                float4 q0 = *(float4*)&wlds[er * 36 + ec * 8];
                float4 q1 = *(float4*)&wlds[er * 36 + ec * 8 + 4];
                if (WF32) {
                    float* p = Cf + batch * cfBatch + (long)(grow + er) * ldcf + gcol + ec * 8;
                    *(float4*)p = q0;
                    *(float4*)(p + 4) = q1;
                }
                if (WH16) {
                    half8 o = { (half_t)q0.x, (half_t)q0.y, (half_t)q0.z, (half_t)q0.w,
                                (half_t)q1.x, (half_t)q1.y, (half_t)q1.z, (half_t)q1.w };
                    *(half8*)&Ch[batch * cfBatch + (long)(grow + er) * N + gcol + ec * 8] = o;
                }
                __builtin_amdgcn_s_waitcnt(0);   // drain before next overwrite of wlds
            }
        }
    }
}

// In-place fp16 softmax, plain row order.
__global__ void softmax_h(half_t* __restrict__ S) {
    const long r = blockIdx.x;
    half_t* row = S + r * 1024;
    const int tid = threadIdx.x;
    const int wave = tid >> 6, lane = tid & 63;

    half4 h4 = ((const half4*)row)[tid];
    float v0 = (float)h4[0], v1 = (float)h4[1], v2 = (float)h4[2], v3 = (float)h4[3];
    float mx = fmaxf(fmaxf(v0, v1), fmaxf(v2, v3));
#pragma unroll
    for (int off = 32; off > 0; off >>= 1)
        mx = fmaxf(mx, __shfl_xor(mx, off));
    __shared__ float rmx[4], rsm[4];
    if (lane == 0) rmx[wave] = mx;
    __syncthreads();
    mx = fmaxf(fmaxf(rmx[0], rmx[1]), fmaxf(rmx[2], rmx[3]));

    float e0 = __expf(v0 - mx), e1 = __expf(v1 - mx);
    float e2 = __expf(v2 - mx), e3 = __expf(v3 - mx);
    float s = e0 + e1 + e2 + e3;
#pragma unroll
    for (int off = 32; off > 0; off >>= 1)
        s += __shfl_xor(s, off);
    if (lane == 0) rsm[wave] = s;
    __syncthreads();
    s = rsm[0] + rsm[1] + rsm[2] + rsm[3];

    const float inv = 1.0f / s;
    half4 o = { (half_t)(e0 * inv), (half_t)(e1 * inv), (half_t)(e2 * inv), (half_t)(e3 * inv) };
    ((half4*)row)[tid] = o;
}

// both weight matrices in one dispatch (1024 blocks x 256 thr, 1 float4 each x2)
__global__ void cvt_w2(const float4* __restrict__ w1, half4* __restrict__ d1,
                       const float4* __restrict__ w2, half4* __restrict__ d2) {
    const int i = blockIdx.x * 256 + threadIdx.x;   // 262144 float4s per matrix
    const float4 a = w1[i];
    d1[i] = (half4){ (half_t)a.x, (half_t)a.y, (half_t)a.z, (half_t)a.w };
    const float4 b = w2[i];
    d2[i] = (half4){ (half_t)b.x, (half_t)b.y, (half_t)b.z, (half_t)b.w };
}

extern "C" void kernel_launch(void* const* d_in, const int* in_sizes, int n_in,
                              void* d_out, int out_size, void* d_ws, size_t ws_size,
                              hipStream_t stream) {
    const float* h  = (const float*)d_in[0];
    const float* s  = (const float*)d_in[1];
    const float* Wh = (const float*)d_in[2];
    const float* bh = (const float*)d_in[3];
    const float* Ws = (const float*)d_in[4];
    const float* bs = (const float*)d_in[5];

    const long MB = 16384;   // B*TH
    const long D  = 1024;

    // workspace carve (~132 MB)
    char* w = (char*)d_ws;
    half_t* sc16 = (half_t*)w;  w += MB * D * 2;   // 32MB fp16 scores/probs
    half_t* Wh16 = (half_t*)w;  w += D * D * 2;
    half_t* Ws16 = (half_t*)w;  w += D * D * 2;
    half_t* hp16 = (half_t*)w;  w += MB * D * 2;
    half_t* sp16 = (half_t*)w;  w += MB * D * 2;
    half_t* hpT  = (half_t*)w;  w += MB * D * 2;   // [16][o][t]

    (void)hipFuncSetAttribute(reinterpret_cast<const void*>(&gemm256<0,1,1,1,0>),
                        hipFuncAttributeMaxDynamicSharedMemorySize, 131072);
    (void)hipFuncSetAttribute(reinterpret_cast<const void*>(&gemm256<0,1,0,1,0>),
                        hipFuncAttributeMaxDynamicSharedMemorySize, 131072);
    (void)hipFuncSetAttribute(reinterpret_cast<const void*>(&gemm256<0,1,0,0,1>),
                        hipFuncAttributeMaxDynamicSharedMemorySize, 131072);
    (void)hipFuncSetAttribute(reinterpret_cast<const void*>(&gemm256<1,0,0,0,1>),
                        hipFuncAttributeMaxDynamicSharedMemorySize, 131072);

    cvt_w2<<<1024, 256, 0, stream>>>((const float4*)Wh, (half4*)Wh16,
                                     (const float4*)Ws, (half4*)Ws16);

    // GEMM1: hp = h*Wh^T + bh (A from f32, fused cvt; fp16 out + coalesced hpT)
    gemm256<0,1,1,1,0><<<dim3(64, 4, 1), 512, 131072, stream>>>(
        nullptr, h, Wh16, bh, nullptr, hp16, hpT, 1024, 1024, 1024, 0, 0, 0, 0);
    // GEMM2: sp = s*Ws^T + bs
    gemm256<0,1,0,1,0><<<dim3(64, 4, 1), 512, 131072, stream>>>(
        nullptr, s, Ws16, bs, nullptr, sp16, nullptr, 1024, 1024, 1024, 0, 0, 0, 0);
    // GEMM3: scores[b] = hp_b * sp_b^T -> fp16, XCD-batch swizzle
    gemm256<0,1,0,0,1><<<dim3(4, 4, 16), 512, 131072, stream>>>(
        hp16, nullptr, sp16, nullptr, nullptr, sc16, nullptr, 1024, 1024, 1024,
        1048576L, 1048576L, 1048576L, 0);
    // softmax over j, fp16 in place
    softmax_h<<<16384, 256, 0, stream>>>(sc16);
    // GEMM4: out[b] = probs_b * hpT_b^T (f32 -> d_out), XCD-batch swizzle
    gemm256<1,0,0,0,1><<<dim3(4, 4, 16), 512, 131072, stream>>>(
        sc16, nullptr, hpT, nullptr, (float*)d_out, nullptr, nullptr,
        1024, 1024, 1024, 1048576L, 1048576L, 1048576L, 1024);
}

// Round 22
// 206.456 us; speedup vs baseline: 1.0913x; 1.0134x over previous
//
#include <hip/hip_runtime.h>
#include <hip/hip_bf16.h>
#include <stdint.h>

// B=16, TH=TS=HS=WS=1024
// res[b,i,o] = sum_j softmax_j(hp[b,i,:].sp[b,j,:]) * hp[b,j,o]
// hp = h*Wh^T + bh ; sp = s*Ws^T + bs
// R22 = R21 (209us) + G1/G2 merged into one z=2 dispatch (removes the
// device-wide barrier between them: z=1 blocks start on CUs freed by z=0's
// tail). RSA fused-cvt A staging, fp16 scores, SWZ G3/G4, coalesced hpT.

typedef _Float16 half_t;
typedef __attribute__((ext_vector_type(8))) _Float16 half8;   // 4 VGPR
typedef __attribute__((ext_vector_type(4))) _Float16 half4;
typedef __attribute__((ext_vector_type(4))) float floatx4;

__device__ __forceinline__ void gl2lds16(const void* g, void* l) {
    __builtin_amdgcn_global_load_lds(
        (const __attribute__((address_space(1))) uint32_t*)(uintptr_t)g,
        (__attribute__((address_space(3))) uint32_t*)(uintptr_t)l,
        16, 0, 0);
}

#define NT16 16   // K = 1024, BK = 64

// C[r][c] = sum_k A[r][k]*B[c][k] (+bias[c]); operands K-major (B^T GEMM).
// 256x256 tile, 8 waves (2Mx4N), per-wave 128x64, double-buffered 128KB LDS.
// Swizzle: rows are 128B (=32 banks); XOR byte bits 4-6 with row&7.
// RSA: A staged from f32 global (load->cvt->swizzled ds_write).
// SWZ: grid (4,4,16); batch remapped so a batch's 16 tiles share one XCD.
// MERGE: grid (64,4,2); z=0 -> (A32,B,bias,Ch,+hpT), z=1 -> (A32b,B2,bias2,Ch2).
template<int WF32, int WH16, int WH16T, int RSA, int SWZ, int MERGE>
__global__ __launch_bounds__(512, 2) void gemm256(
    const half_t* __restrict__ A, const float* __restrict__ A32,
    const half_t* __restrict__ B,
    const float* __restrict__ bias,
    float* __restrict__ Cf, half_t* __restrict__ Ch, half_t* __restrict__ ChT,
    int lda, int ldb, int N,
    long aBatch, long bBatch, long cfBatch, int ldcf,
    const float* __restrict__ A32b, const half_t* __restrict__ B2,
    const float* __restrict__ bias2, half_t* __restrict__ Ch2)
{
    extern __shared__ char smem[];   // [2][ A:32KB | B:32KB ] = 128KB

    const int tid  = threadIdx.x;
    const int wave = tid >> 6;
    const int lane = tid & 63;
    const int wr = wave >> 2;        // 0..1 -> rows wr*128..+127
    const int wc = wave & 3;         // 0..3 -> cols wc*64..+63
    const int lr = lane & 15, lg = lane >> 4;

    long batch; int row0, col0;
    if constexpr (SWZ) {
        const int lin = blockIdx.x + (blockIdx.y << 2) + (blockIdx.z << 4);
        const int xcd = lin & 7, per = lin >> 3;          // 32 blocks per XCD
        batch = (xcd << 1) | (per >> 4);                  // 2 batches per XCD
        const int wt = per & 15;
        row0 = (wt & 3) * 256;
        col0 = (wt >> 2) * 256;
    } else {
        batch = MERGE ? 0 : blockIdx.z;
        row0 = blockIdx.x * 256;
        col0 = blockIdx.y * 256;
    }

    // merged-path pointer select (block-uniform)
    const int zz = MERGE ? (int)blockIdx.z : 0;
    const float*  A32s  = (MERGE && zz) ? A32b  : A32;
    const half_t* Bsel  = (MERGE && zz) ? B2    : B;
    const float*  bsel  = (MERGE && zz) ? bias2 : bias;
    half_t*       Chsel = (MERGE && zz) ? Ch2   : Ch;
    const int doT = WH16T && (!MERGE || zz == 0);

    const half_t* Bb = Bsel + batch * bBatch;

    floatx4 acc[8][4];
#pragma unroll
    for (int m = 0; m < 8; ++m)
#pragma unroll
        for (int n = 0; n < 4; ++n)
            acc[m][n] = (floatx4){0.f, 0.f, 0.f, 0.f};

    // hoisted B stage source offsets (pre-swizzled global src for gl2lds):
    long bOff[2][2];
    long aOffG[2][2];                 // A gl2lds path (non-RSA)
#pragma unroll
    for (int hh = 0; hh < 2; ++hh)
#pragma unroll
        for (int i = 0; i < 2; ++i) {
            const int off = hh * 16384 + i * 8192 + tid * 16;
            const int e = off ^ (((off >> 7) & 7) << 4);
            const int r = e >> 7, cb = e & 127;
            bOff[hh][i] = (long)(col0 + r) * (long)(ldb * 2) + cb;
            if constexpr (!RSA)
                aOffG[hh][i] = (long)(row0 + r) * (long)(lda * 2) + cb;
        }

    const int wave_s = __builtin_amdgcn_readfirstlane(wave);
    auto stageB = [&](int buf, int kk) {
#pragma unroll
        for (int hh = 0; hh < 2; ++hh)
#pragma unroll
            for (int i = 0; i < 2; ++i)
                gl2lds16((const char*)Bb + bOff[hh][i] + (long)kk * 2,
                         smem + buf * 65536 + 32768 + hh * 16384 + i * 8192 + wave_s * 1024);
    };
    auto stageA16 = [&](int buf, int kk) {   // non-RSA: fp16 A via gl2lds
        const half_t* Ab = A + batch * aBatch;
#pragma unroll
        for (int hh = 0; hh < 2; ++hh)
#pragma unroll
            for (int i = 0; i < 2; ++i)
                gl2lds16((const char*)Ab + aOffG[hh][i] + (long)kk * 2,
                         smem + buf * 65536 + hh * 16384 + i * 8192 + wave_s * 1024);
    };

    // RSA chunk coords (4 chunks x 16B fp16 per thread)
    int rsaRow[4], rsaKb[4];
#pragma unroll
    for (int c = 0; c < 4; ++c) {
        const int off = c * 8192 + tid * 16;
        rsaRow[c] = off >> 7;
        rsaKb[c]  = off & 127;
    }

    // fragment-read bases (swizzle folded)
    uint32_t aof0 = (uint32_t)((wr * 128 + lr) * 128 + ((lg * 16) ^ ((lr & 7) << 4)));
    uint32_t aof1 = (uint32_t)((wr * 128 + lr) * 128 + ((64 + lg * 16) ^ ((lr & 7) << 4)));
    uint32_t bof0 = (uint32_t)(32768 + (wc * 64 + lr) * 128 + ((lg * 16) ^ ((lr & 7) << 4)));
    uint32_t bof1 = (uint32_t)(32768 + (wc * 64 + lr) * 128 + ((64 + lg * 16) ^ ((lr & 7) << 4)));

    // staging of A for RSA: load 8xfloat4 -> cvt -> 4x ds_write_b128 (swizzled)
    auto rsaLoad = [&](float4 (&fv)[4][2], int kk) {
#pragma unroll
        for (int c = 0; c < 4; ++c) {
            const float* src = A32s + batch * aBatch
                             + (long)(row0 + rsaRow[c]) * lda + kk + (rsaKb[c] >> 1);
            fv[c][0] = *(const float4*)src;
            fv[c][1] = *(const float4*)(src + 4);
        }
    };
    auto rsaWrite = [&](float4 (&fv)[4][2], int buf) {
#pragma unroll
        for (int c = 0; c < 4; ++c) {
            half8 o = { (half_t)fv[c][0].x, (half_t)fv[c][0].y, (half_t)fv[c][0].z, (half_t)fv[c][0].w,
                        (half_t)fv[c][1].x, (half_t)fv[c][1].y, (half_t)fv[c][1].z, (half_t)fv[c][1].w };
            *(half8*)(smem + buf * 65536 + rsaRow[c] * 128
                      + (rsaKb[c] ^ ((rsaRow[c] & 7) << 4))) = o;
        }
    };

    // ---- prologue: stage tile 0, sync.
    if constexpr (RSA) {
        float4 fv[4][2];
        rsaLoad(fv, 0);
        stageB(0, 0);
        rsaWrite(fv, 0);
    } else {
        stageA16(0, 0);
        stageB(0, 0);
    }
    __syncthreads();

    for (int t = 0; t < NT16; ++t) {
        const int nxt = (t & 1) ^ 1;
        const int k1 = (t + 1) * 64;

        // (1) issue next-tile staging loads first (T3 recipe)
        float4 fv[4][2];
        if (t + 1 < NT16) {
            if constexpr (RSA) {
                rsaLoad(fv, k1);     // f32 loads in flight; writes deferred below
                stageB(nxt, k1);
            } else {
                stageA16(nxt, k1);
                stageB(nxt, k1);
            }
        }

        // (2) ds_reads of tile t
        half8 aF[4][2], bF[4][2];
#pragma unroll
        for (int ni = 0; ni < 4; ++ni) {
            bF[ni][0] = *(const half8*)(smem + bof0 + ni * 2048);
            bF[ni][1] = *(const half8*)(smem + bof1 + ni * 2048);
        }
#pragma unroll
        for (int mi = 0; mi < 4; ++mi) {
            aF[mi][0] = *(const half8*)(smem + aof0 + mi * 2048);
            aF[mi][1] = *(const half8*)(smem + aof1 + mi * 2048);
        }

        // (2b) RSA: convert + swizzled LDS writes for tile t+1
        if (RSA && t + 1 < NT16) rsaWrite(fv, nxt);

        // (3) MFMA of tile t (two 32-MFMA halves)
#pragma unroll
        for (int mi = 0; mi < 4; ++mi)
#pragma unroll
            for (int ni = 0; ni < 4; ++ni)
#pragma unroll
                for (int ks = 0; ks < 2; ++ks)
                    acc[mi][ni] = __builtin_amdgcn_mfma_f32_16x16x32_f16(
                        aF[mi][ks], bF[ni][ks], acc[mi][ni], 0, 0, 0);
#pragma unroll
        for (int mi = 0; mi < 4; ++mi) {
            aF[mi][0] = *(const half8*)(smem + aof0 + (4 + mi) * 2048);
            aF[mi][1] = *(const half8*)(smem + aof1 + (4 + mi) * 2048);
        }
#pragma unroll
        for (int mi = 0; mi < 4; ++mi)
#pragma unroll
            for (int ni = 0; ni < 4; ++ni)
#pragma unroll
                for (int ks = 0; ks < 2; ++ks)
                    acc[4 + mi][ni] = __builtin_amdgcn_mfma_f32_16x16x32_f16(
                        aF[mi][ks], bF[ni][ks], acc[4 + mi][ni], 0, 0, 0);

        // (4) one barrier per K-step
        __syncthreads();
        aof0 ^= 65536; aof1 ^= 65536; bof0 ^= 65536; bof1 ^= 65536;
    }

    // bias values for this wave's 4 n-tiles
    float bv[4];
#pragma unroll
    for (int n = 0; n < 4; ++n)
        bv[n] = bsel ? bsel[col0 + wc * 64 + n * 16 + lr] : 0.f;

    // ---- hpT phase: per-wave 16KB LDS [64 o][128 t] fp16,
    // byte bits 4-6 XOR'd with o&7; then 256B-contiguous row stores.
    if (WH16T) {
        if (doT) {
            char* tb = smem + wave * 16384;
#pragma unroll
            for (int m = 0; m < 8; ++m)
#pragma unroll
                for (int n = 0; n < 4; ++n) {
                    const int o_l = n * 16 + lr;                  // 0..63
                    const uint32_t x = (uint32_t)(o_l & 7) << 4;
                    floatx4 v = acc[m][n];
                    half4 pk = { (half_t)(v[0] + bv[n]), (half_t)(v[1] + bv[n]),
                                 (half_t)(v[2] + bv[n]), (half_t)(v[3] + bv[n]) };
                    *(half4*)(tb + o_l * 256 + (((uint32_t)(m * 32 + lg * 8)) ^ x)) = pk;
                }
#pragma unroll
            for (int seg = 0; seg < 16; ++seg) {
                const int o_l = seg * 4 + (lane >> 4);
                const uint32_t cb = (uint32_t)((lane & 15) * 16) ^ ((uint32_t)(o_l & 7) << 4);
                half8 v = *(const half8*)(tb + o_l * 256 + cb);
                const long o_g = col0 + wc * 64 + o_l;
                const int  t_g = row0 + wr * 128 + (lane & 15) * 8;
                *(half8*)&ChT[(batch + (long)(t_g >> 10)) * 1048576
                              + o_g * 1024 + (t_g & 1023)] = v;
            }
            __builtin_amdgcn_s_waitcnt(0);   // drain before wlds reuses this region
        }
    }

    // ---- main epilogue: transpose acc through LDS for coalesced 16B stores.
    {
        float* wlds = (float*)(smem + wave * 16384);   // own region (16x36 f32)
        const int er = lane >> 2, ec = lane & 3;
#pragma unroll
        for (int m = 0; m < 8; ++m) {
#pragma unroll
            for (int np = 0; np < 2; ++np) {
#pragma unroll
                for (int n2 = 0; n2 < 2; ++n2)
#pragma unroll
                    for (int j = 0; j < 4; ++j)
                        wlds[(lg * 4 + j) * 36 + n2 * 16 + lr] =
                            acc[m][np * 2 + n2][j] + bv[np * 2 + n2];
                const int grow = row0 + wr * 128 + m * 16;
                const int gcol = col0 + wc * 64 + np * 32;
                float4 q0 = *(float4*)&wlds[er * 36 + ec * 8];
                float4 q1 = *(float4*)&wlds[er * 36 + ec * 8 + 4];
                if (WF32) {
                    float* p = Cf + batch * cfBatch + (long)(grow + er) * ldcf + gcol + ec * 8;
                    *(float4*)p = q0;
                    *(float4*)(p + 4) = q1;
                }
                if (WH16) {
                    half8 o = { (half_t)q0.x, (half_t)q0.y, (half_t)q0.z, (half_t)q0.w,
                                (half_t)q1.x, (half_t)q1.y, (half_t)q1.z, (half_t)q1.w };
                    *(half8*)&Chsel[batch * cfBatch + (long)(grow + er) * N + gcol + ec * 8] = o;
                }
                __builtin_amdgcn_s_waitcnt(0);   // drain before next overwrite of wlds
            }
        }
    }
}

// In-place fp16 softmax, plain row order.
__global__ void softmax_h(half_t* __restrict__ S) {
    const long r = blockIdx.x;
    half_t* row = S + r * 1024;
    const int tid = threadIdx.x;
    const int wave = tid >> 6, lane = tid & 63;

    half4 h4 = ((const half4*)row)[tid];
    float v0 = (float)h4[0], v1 = (float)h4[1], v2 = (float)h4[2], v3 = (float)h4[3];
    float mx = fmaxf(fmaxf(v0, v1), fmaxf(v2, v3));
#pragma unroll
    for (int off = 32; off > 0; off >>= 1)
        mx = fmaxf(mx, __shfl_xor(mx, off));
    __shared__ float rmx[4], rsm[4];
    if (lane == 0) rmx[wave] = mx;
    __syncthreads();
    mx = fmaxf(fmaxf(rmx[0], rmx[1]), fmaxf(rmx[2], rmx[3]));

    float e0 = __expf(v0 - mx), e1 = __expf(v1 - mx);
    float e2 = __expf(v2 - mx), e3 = __expf(v3 - mx);
    float s = e0 + e1 + e2 + e3;
#pragma unroll
    for (int off = 32; off > 0; off >>= 1)
        s += __shfl_xor(s, off);
    if (lane == 0) rsm[wave] = s;
    __syncthreads();
    s = rsm[0] + rsm[1] + rsm[2] + rsm[3];

    const float inv = 1.0f / s;
    half4 o = { (half_t)(e0 * inv), (half_t)(e1 * inv), (half_t)(e2 * inv), (half_t)(e3 * inv) };
    ((half4*)row)[tid] = o;
}

// both weight matrices in one dispatch (1024 blocks x 256 thr, 1 float4 each x2)
__global__ void cvt_w2(const float4* __restrict__ w1, half4* __restrict__ d1,
                       const float4* __restrict__ w2, half4* __restrict__ d2) {
    const int i = blockIdx.x * 256 + threadIdx.x;   // 262144 float4s per matrix
    const float4 a = w1[i];
    d1[i] = (half4){ (half_t)a.x, (half_t)a.y, (half_t)a.z, (half_t)a.w };
    const float4 b = w2[i];
    d2[i] = (half4){ (half_t)b.x, (half_t)b.y, (half_t)b.z, (half_t)b.w };
}

extern "C" void kernel_launch(void* const* d_in, const int* in_sizes, int n_in,
                              void* d_out, int out_size, void* d_ws, size_t ws_size,
                              hipStream_t stream) {
    const float* h  = (const float*)d_in[0];
    const float* s  = (const float*)d_in[1];
    const float* Wh = (const float*)d_in[2];
    const float* bh = (const float*)d_in[3];
    const float* Ws = (const float*)d_in[4];
    const float* bs = (const float*)d_in[5];

    const long MB = 16384;   // B*TH
    const long D  = 1024;

    // workspace carve (~132 MB)
    char* w = (char*)d_ws;
    half_t* sc16 = (half_t*)w;  w += MB * D * 2;   // 32MB fp16 scores/probs
    half_t* Wh16 = (half_t*)w;  w += D * D * 2;
    half_t* Ws16 = (half_t*)w;  w += D * D * 2;
    half_t* hp16 = (half_t*)w;  w += MB * D * 2;
    half_t* sp16 = (half_t*)w;  w += MB * D * 2;
    half_t* hpT  = (half_t*)w;  w += MB * D * 2;   // [16][o][t]

    (void)hipFuncSetAttribute(reinterpret_cast<const void*>(&gemm256<0,1,1,1,0,1>),
                        hipFuncAttributeMaxDynamicSharedMemorySize, 131072);
    (void)hipFuncSetAttribute(reinterpret_cast<const void*>(&gemm256<0,1,0,0,1,0>),
                        hipFuncAttributeMaxDynamicSharedMemorySize, 131072);
    (void)hipFuncSetAttribute(reinterpret_cast<const void*>(&gemm256<1,0,0,0,1,0>),
                        hipFuncAttributeMaxDynamicSharedMemorySize, 131072);

    cvt_w2<<<1024, 256, 0, stream>>>((const float4*)Wh, (half4*)Wh16,
                                     (const float4*)Ws, (half4*)Ws16);

    // GEMM1+2 merged (z=0: hp = h*Wh^T + bh, + coalesced hpT; z=1: sp = s*Ws^T + bs)
    gemm256<0,1,1,1,0,1><<<dim3(64, 4, 2), 512, 131072, stream>>>(
        nullptr, h, Wh16, bh, nullptr, hp16, hpT, 1024, 1024, 1024, 0, 0, 0, 0,
        s, Ws16, bs, sp16);
    // GEMM3: scores[b] = hp_b * sp_b^T -> fp16, XCD-batch swizzle
    gemm256<0,1,0,0,1,0><<<dim3(4, 4, 16), 512, 131072, stream>>>(
        hp16, nullptr, sp16, nullptr, nullptr, sc16, nullptr, 1024, 1024, 1024,
        1048576L, 1048576L, 1048576L, 0,
        nullptr, nullptr, nullptr, nullptr);
    // softmax over j, fp16 in place
    softmax_h<<<16384, 256, 0, stream>>>(sc16);
    // GEMM4: out[b] = probs_b * hpT_b^T (f32 -> d_out), XCD-batch swizzle
    gemm256<1,0,0,0,1,0><<<dim3(4, 4, 16), 512, 131072, stream>>>(
        sc16, nullptr, hpT, nullptr, (float*)d_out, nullptr, nullptr,
        1024, 1024, 1024, 1048576L, 1048576L, 1048576L, 1024,
        nullptr, nullptr, nullptr, nullptr);
}